// Round 1
// 226.873 us; speedup vs baseline: 1.0041x; 1.0041x over previous
//
#include <hip/hip_runtime.h>
#include <hip/hip_cooperative_groups.h>

namespace cg = cooperative_groups;

// Problem: x [T, B, C, H, W] = [5, 32, 128, 32, 32] fp32, LIF scan.
// R8 post-mortem: five lif_step kernels each <50us but summing to ~228us --
// per-step effective BW only ~1.8 TB/s. The gap is structural: 4 full-device
// drains at kernel boundaries + a 16MB mem-state round-trip per step + cold
// ema-chain reconstruction. Traffic floor is 240MB (160 read + 80 write)
// ~= 38us @ 6.3 TB/s.
// R9: ONE cooperative kernel. mem state stays in registers for all 5 steps;
// the only cross-block coupling (per-channel spike count, 128 u32 per step)
// crosses a grid.sync() as agent-scope u32 partials. Next-step xe/xi loads
// are prefetched before the reduce+sync so HBM reads pipeline across the
// barrier. Per-element arithmetic and the ema/inhw float sequence are
// bit-identical to R8 (absmax must stay exactly 0.0).
constexpr int T    = 5;
constexpr int C    = 128;
constexpr int NPT4 = 32 * C * 1024 / 4;    // f4 per timestep = 1,048,576

constexpr int SBLOCKS  = 1024;
constexpr int STHREADS = 256;
constexpr int KT       = 4;                // (b,c) tiles per block (4096/1024)

// d_ws layout: [ partials u32[T][SBLOCKS] | mem float4[NPT4] ]
// (coop path uses only the partials region; mem region kept for the R8 path)
constexpr size_t PART_BYTES = (size_t)T * SBLOCKS * sizeof(unsigned int); // 20480
constexpr size_t WS_NEEDED  = PART_BYTES + (size_t)NPT4 * 16;             // ~16.8MB

// ---- R9: single cooperative kernel, mem in registers ----
__global__ __launch_bounds__(STHREADS, 4)
void lif_coop(const float4* __restrict__ xe4,
              const float4* __restrict__ xi4,
              const float* __restrict__ alpha_raw,
              const float* __restrict__ beta_raw,
              float4* __restrict__ out4,
              unsigned int* __restrict__ partials) {
#pragma clang fp contract(off)
  const int blk = blockIdx.x;
  const int tid = threadIdx.x;
  const int c   = blk & (C - 1);           // all KT tiles of this block are channel c
  __shared__ float s_inhw;
  __shared__ unsigned int wsum[STHREADS / 64];

  const float alpha = 4.0f / (1.0f + expf(-alpha_raw[0])); // 4*sigmoid
  const float beta  = 1.0f / (1.0f + expf(-beta_raw[0]));  // sigmoid

  const size_t fi0 = (size_t)blk * 256 + tid;

  // double-buffered input regs: e/i = current step, en/ix = prefetched next
  float4 e[KT], i[KT], en[KT], ix[KT];
#pragma unroll
  for (int k = 0; k < KT; ++k) {
    const size_t fi = fi0 + (size_t)(k * SBLOCKS) * 256;
    e[k] = xe4[fi];
    i[k] = xi4[fi];
  }

  float mv[KT][4];                         // membrane state: registers, all 5 steps
#pragma unroll
  for (int k = 0; k < KT; ++k)
#pragma unroll
    for (int j = 0; j < 4; ++j) mv[k][j] = 0.0f;

  float inhw = 0.0f;                       // inh_weight starts 0
  float ema  = 0.17f;                      // EMA_INIT; live only in tid 0
  cg::grid_group grid = cg::this_grid();

  for (int t = 0; t < T; ++t) {
    const size_t tb = (size_t)t * NPT4;

    // prefetch t+1 inputs BEFORE compute+reduce+sync: the loads are
    // independent of inhw, so they pipeline across the grid barrier.
    if (t < T - 1) {
      const size_t tb1 = tb + NPT4;
#pragma unroll
      for (int k = 0; k < KT; ++k) {
        const size_t fi = fi0 + (size_t)(k * SBLOCKS) * 256;
        en[k] = xe4[tb1 + fi];
        ix[k] = xi4[tb1 + fi];
      }
    }

    unsigned int local = 0;
#pragma unroll
    for (int k = 0; k < KT; ++k) {
      const size_t fi = fi0 + (size_t)(k * SBLOCKS) * 256;
      const float xe[4] = {e[k].x, e[k].y, e[k].z, e[k].w};
      const float xi[4] = {i[k].x, i[k].y, i[k].z, i[k].w};
      float sv[4];
#pragma unroll
      for (int j = 0; j < 4; ++j) {
        // identical arithmetic to R5/R7/R8 (absmax exactly 0.0): IEEE divide,
        // literal python op order, contract off
        const float e_in = xe[j] / (1.0f + alpha * xi[j]);
        const float a  = 0.5f * mv[k][j];
        const float bb = a + e_in;
        const float d  = (beta * xi[j]) * (1.0f - inhw);
        const float m  = bb - d;
        const float x  = m - 0.5f;             // mem - V_TH
        const float s  = (x >= 0.0f) ? 1.0f : 0.0f;
        local += (x >= 0.0f) ? 1u : 0u;
        mv[k][j] = m - 0.5f * s;               // soft reset
        sv[j] = s;
      }
      float4 s4; s4.x = sv[0]; s4.y = sv[1]; s4.z = sv[2]; s4.w = sv[3];
      out4[tb + fi] = s4;
    }
    if (t == T - 1) break;                     // t=4 coupling never read

    // block reduction of spike count
#pragma unroll
    for (int off = 32; off > 0; off >>= 1) local += __shfl_down(local, off);
    if ((tid & 63) == 0) wsum[tid >> 6] = local;
    __syncthreads();
    if (tid == 0) {
      const unsigned int total = wsum[0] + wsum[1] + wsum[2] + wsum[3];
      // agent scope: visible across XCD L2s independent of grid.sync internals
      __hip_atomic_store(&partials[t * SBLOCKS + blk], total,
                         __ATOMIC_RELEASE, __HIP_MEMORY_SCOPE_AGENT);
    }

    grid.sync();

    if (tid == 0) {
      unsigned int tot = 0;
#pragma unroll
      for (int q = 0; q < 8; ++q)
        tot += __hip_atomic_load(&partials[t * SBLOCKS + c + q * C],
                                 __ATOMIC_ACQUIRE, __HIP_MEMORY_SCOPE_AGENT);
      // same float sequence as the R8 reconstruction chain, kept incrementally
      const float mean = (float)tot * (1.0f / 32768.0f);   // exact /2^15
      ema = 0.9f * ema + 0.1f * mean;
      const float s_lo = 1.0f / (1.0f + expf(-(0.17f - ema))); // sig(LOWER-ema)
      const float s_hi = 1.0f / (1.0f + expf(-(ema - 0.23f))); // sig(ema-UPPER)
      s_inhw = 4.0f * (s_lo - s_hi);
    }
    __syncthreads();
    inhw = s_inhw;

#pragma unroll
    for (int k = 0; k < KT; ++k) { e[k] = en[k]; i[k] = ix[k]; }
  }
}

// ---- R8 path: one plain kernel per timestep (fallback if no coop launch) ----
__global__ __launch_bounds__(STHREADS)
void lif_step(const float4* __restrict__ xe4,
              const float4* __restrict__ xi4,
              const float* __restrict__ alpha_raw,
              const float* __restrict__ beta_raw,
              float4* __restrict__ out4,
              float4* __restrict__ memb,
              unsigned int* __restrict__ partials,
              int t) {
#pragma clang fp contract(off)
  const int blk = blockIdx.x;
  const int tid = threadIdx.x;
  const int c   = blk & (C - 1);

  __shared__ float s_inhw;
  if (tid == 0) {
    float inhw = 0.0f;
    if (t > 0) {
      float ema = 0.17f;
      for (int s = 0; s < t; ++s) {
        unsigned int tot = 0;
#pragma unroll
        for (int i = 0; i < 8; ++i) tot += partials[s * SBLOCKS + c + i * C];
        const float mean = (float)tot * (1.0f / 32768.0f);
        ema = 0.9f * ema + 0.1f * mean;
      }
      const float s_lo = 1.0f / (1.0f + expf(-(0.17f - ema)));
      const float s_hi = 1.0f / (1.0f + expf(-(ema - 0.23f)));
      inhw = 4.0f * (s_lo - s_hi);
    }
    s_inhw = inhw;
  }
  __syncthreads();
  const float inhw  = s_inhw;
  const float alpha = 4.0f / (1.0f + expf(-alpha_raw[0]));
  const float beta  = 1.0f / (1.0f + expf(-beta_raw[0]));

  unsigned int local = 0;
  const size_t tb = (size_t)t * NPT4;
#pragma unroll
  for (int k = 0; k < KT; ++k) {
    const size_t fi = (size_t)(k * SBLOCKS + blk) * 256 + tid;
    const float4 e4 = xe4[tb + fi];
    const float4 i4 = xi4[tb + fi];
    float4 m4 = {0.0f, 0.0f, 0.0f, 0.0f};
    if (t > 0) m4 = memb[fi];
    const float xe[4] = {e4.x, e4.y, e4.z, e4.w};
    const float xi[4] = {i4.x, i4.y, i4.z, i4.w};
    float mv[4] = {m4.x, m4.y, m4.z, m4.w};
    float sv[4];
#pragma unroll
    for (int j = 0; j < 4; ++j) {
      const float e_in = xe[j] / (1.0f + alpha * xi[j]);
      const float a  = 0.5f * mv[j];
      const float bb = a + e_in;
      const float d  = (beta * xi[j]) * (1.0f - inhw);
      const float m  = bb - d;
      const float x  = m - 0.5f;
      const float s  = (x >= 0.0f) ? 1.0f : 0.0f;
      local += (x >= 0.0f) ? 1u : 0u;
      mv[j] = m - 0.5f * s;
      sv[j] = s;
    }
    float4 s4; s4.x = sv[0]; s4.y = sv[1]; s4.z = sv[2]; s4.w = sv[3];
    out4[tb + fi] = s4;
    if (t < T - 1) {
      float4 nm; nm.x = mv[0]; nm.y = mv[1]; nm.z = mv[2]; nm.w = mv[3];
      memb[fi] = nm;
    }
  }

  if (t < T - 1) {
#pragma unroll
    for (int off = 32; off > 0; off >>= 1) local += __shfl_down(local, off);
    __shared__ unsigned int wsum[STHREADS / 64];
    if ((tid & 63) == 0) wsum[tid >> 6] = local;
    __syncthreads();
    if (tid == 0)
      partials[t * SBLOCKS + blk] = wsum[0] + wsum[1] + wsum[2] + wsum[3];
  }
}

// ---- fallback: R7's passing redundant-pair kernel (used only if ws too small)
constexpr int FTHREADS = 1024;
constexpr int FWAVES   = FTHREADS / 64;
constexpr int FBLOCKS  = 2 * C;
constexpr int FK       = 8;

__global__ __launch_bounds__(FTHREADS)
void lif_fallback(const float* __restrict__ xe_g, const float* __restrict__ xi_g,
                  const float* __restrict__ alpha_raw,
                  const float* __restrict__ beta_raw, float* __restrict__ out) {
#pragma clang fp contract(off)
  const int blk = blockIdx.x, c = blk & (C - 1), half = blk >> 7;
  const int tid = threadIdx.x, wave = tid >> 6, lane = tid & 63;
  __shared__ unsigned int wsum[T - 1][FWAVES];
  const float alpha = 4.0f / (1.0f + expf(-alpha_raw[0]));
  const float beta  = 1.0f / (1.0f + expf(-beta_raw[0]));
  float mem[FK][4];
#pragma unroll
  for (int k = 0; k < FK; ++k)
#pragma unroll
    for (int j = 0; j < 4; ++j) mem[k][j] = 0.0f;
  float ema = 0.17f, inhw = 0.0f;
  const float4* xe4 = (const float4*)xe_g;
  const float4* xi4 = (const float4*)xi_g;
  float4* o4 = (float4*)out;
  auto gidx = [&](int t, int k) -> size_t {
    const int b = k * (FTHREADS / 256) + (tid >> 8);
    return (size_t)t * NPT4 + (size_t)(b * C + c) * 256 + (tid & 255);
  };
  for (int t = 0; t < T; ++t) {
    float4 e4[FK], i4[FK];
#pragma unroll
    for (int k = 0; k < FK; ++k) { const size_t idx = gidx(t, k); e4[k] = xe4[idx]; i4[k] = xi4[idx]; }
    unsigned int local = 0;
#pragma unroll
    for (int k = 0; k < FK; ++k) {
      const float xe[4] = {e4[k].x, e4[k].y, e4[k].z, e4[k].w};
      const float xi[4] = {i4[k].x, i4[k].y, i4[k].z, i4[k].w};
      float sv[4];
#pragma unroll
      for (int j = 0; j < 4; ++j) {
        const float e_in = xe[j] / (1.0f + alpha * xi[j]);
        const float a = 0.5f * mem[k][j];
        const float bb = a + e_in;
        const float d = (beta * xi[j]) * (1.0f - inhw);
        const float m = bb - d;
        const float x = m - 0.5f;
        const float s = (x >= 0.0f) ? 1.0f : 0.0f;
        local += (x >= 0.0f) ? 1u : 0u;
        mem[k][j] = m - 0.5f * s;
        sv[j] = s;
      }
      if ((k >> 2) == half) {
        float4 s4; s4.x = sv[0]; s4.y = sv[1]; s4.z = sv[2]; s4.w = sv[3];
        o4[gidx(t, k)] = s4;
      }
    }
    if (t == T - 1) break;
#pragma unroll
    for (int off = 32; off > 0; off >>= 1) local += __shfl_down(local, off);
    if (lane == 0) wsum[t][wave] = local;
    __syncthreads();
    unsigned int total = 0;
#pragma unroll
    for (int w = 0; w < FWAVES; ++w) total += wsum[t][w];
    const float mean_spike = (float)total * (1.0f / 32768.0f);
    ema = 0.9f * ema + 0.1f * mean_spike;
    const float s_lo = 1.0f / (1.0f + expf(-(0.17f - ema)));
    const float s_hi = 1.0f / (1.0f + expf(-(ema - 0.23f)));
    inhw = 4.0f * (s_lo - s_hi);
  }
}

extern "C" void kernel_launch(void* const* d_in, const int* in_sizes, int n_in,
                              void* d_out, int out_size, void* d_ws, size_t ws_size,
                              hipStream_t stream) {
  const float* xe = (const float*)d_in[0];
  const float* xi = (const float*)d_in[1];
  const float* ar = (const float*)d_in[2];
  const float* br = (const float*)d_in[3];
  float* out = (float*)d_out;

  // Session-constant capability probe (host-only queries; no stream ops, so
  // graph-capture safe; same path every call).
  static const int coop_ok = [] {
    int dev = 0;
    if (hipGetDevice(&dev) != hipSuccess) return 0;
    int attr = 0;
    if (hipDeviceGetAttribute(&attr, hipDeviceAttributeCooperativeLaunch, dev) != hipSuccess || !attr)
      return 0;
    int nb = 0;
    if (hipOccupancyMaxActiveBlocksPerMultiprocessor(&nb, (const void*)lif_coop,
                                                     STHREADS, 0) != hipSuccess)
      return 0;
    int cus = 0;
    if (hipDeviceGetAttribute(&cus, hipDeviceAttributeMultiprocessorCount, dev) != hipSuccess)
      return 0;
    return (nb * cus >= SBLOCKS) ? 1 : 0;  // co-residency for grid.sync
  }();

  if (coop_ok && ws_size >= PART_BYTES) {
    unsigned int* partials = (unsigned int*)d_ws;
    const float4* xe4 = (const float4*)xe;
    const float4* xi4 = (const float4*)xi;
    float4* out4 = (float4*)out;
    void* args[6];
    args[0] = (void*)&xe4;
    args[1] = (void*)&xi4;
    args[2] = (void*)&ar;
    args[3] = (void*)&br;
    args[4] = (void*)&out4;
    args[5] = (void*)&partials;
    (void)hipLaunchCooperativeKernel((const void*)lif_coop, dim3(SBLOCKS),
                                     dim3(STHREADS), args, 0, stream);
  } else if (ws_size >= WS_NEEDED) {
    unsigned int* partials = (unsigned int*)d_ws;
    float4* memb = (float4*)((char*)d_ws + PART_BYTES);
    const float4* xe4 = (const float4*)xe;
    const float4* xi4 = (const float4*)xi;
    float4* out4 = (float4*)out;
    for (int t = 0; t < T; ++t)
      lif_step<<<dim3(SBLOCKS), dim3(STHREADS), 0, stream>>>(
          xe4, xi4, ar, br, out4, memb, partials, t);
  } else {
    lif_fallback<<<dim3(FBLOCKS), dim3(FTHREADS), 0, stream>>>(xe, xi, ar, br, out);
  }
}